// Round 5
// baseline (2606.812 us; speedup 1.0000x reference)
//
#include <hip/hip_runtime.h>

#define H 51
#define TSEQ 2048
#define BB 16            // batch per block — fills all 16 MFMA columns
#define THREADS 512      // 8 waves: 0-3 = layer-1 stage, 4-7 = layer-2 stage
#define NT 13            // real row-tiles (204 rows / 16)

typedef __attribute__((ext_vector_type(8))) short short8;   // 8 bf16 (MFMA A/B frag)
typedef __attribute__((ext_vector_type(4))) float float4v;  // MFMA C/D frag

#define LOG2E    1.44269504f
#define TWOLOG2E 2.88539008f

// gate rows pre-scaled by log2e (i,f,o) / 2*log2e (g) -> raw v_exp, no mul
__device__ __forceinline__ float sig_pre(float u) {   // sigmoid(g), u = g*log2e
    return __builtin_amdgcn_rcpf(1.0f + __builtin_amdgcn_exp2f(-u));
}
__device__ __forceinline__ float tanh_pre(float u) {  // tanh(g),  u = g*2log2e
    return 1.0f - 2.0f * __builtin_amdgcn_rcpf(1.0f + __builtin_amdgcn_exp2f(u));
}
__device__ __forceinline__ unsigned short bf16_rne(float x) {
    unsigned u = __float_as_uint(x);
    u += 0x7FFF + ((u >> 16) & 1);
    return (unsigned short)(u >> 16);
}
__device__ __forceinline__ float bf16f(unsigned short h) {
    return __uint_as_float(((unsigned)h) << 16);
}

// 2-stage wave pipeline: phase ph: waves 0-3 produce h1(ph), waves 4-7 produce
// h2(ph-1), wave 1 additionally computes y(ph-2). One barrier per phase.
// All LDS reads hit parity p^1, all writes parity p.
// A rows repacked [i_j,f_j,g_j,o_j] per cell -> C/D reg r == gate r, cell = tile*4+quad.
__global__ __launch_bounds__(THREADS, 2)
void lstm_pipe_kernel(const float* __restrict__ input,
                      const float* __restrict__ W_ih1, const float* __restrict__ W_hh1,
                      const float* __restrict__ b_ih1, const float* __restrict__ b_hh1,
                      const float* __restrict__ W_ih2, const float* __restrict__ W_hh2,
                      const float* __restrict__ b_ih2, const float* __restrict__ b_hh2,
                      const float* __restrict__ W_lin, const float* __restrict__ b_lin,
                      float* __restrict__ out)
{
    // [parity][plane hi/lo][kstep][fraglane]
    __shared__ short8 hb1[2][2][2][64];
    __shared__ short8 hb2[2][2][2][64];
    __shared__ float  h2f[2][H * BB];     // fp32 h2 for y (ping-pong)
    __shared__ float  xss[2][64 * 17];    // x chunks, stride 17 = conflict-free
    __shared__ float  ybf[BB][64];        // y buffer (wave1-private)
    __shared__ float  wlin[H + 1];

    const int tid  = threadIdx.x;
    const int wv   = tid >> 6;            // 0..7
    const int lane = tid & 63;
    const int n    = lane & 15;           // MFMA col = batch
    const int qd   = lane >> 4;           // quad
    const int b0   = blockIdx.x * BB;
    const bool isL1 = (wv < 4);
    const int rw   = wv & 3;              // role-wave 0..3

    {   // zero both parities of h-state (512 short8 per array == THREADS)
        short8 z = {0,0,0,0,0,0,0,0};
        (&hb1[0][0][0][0])[tid] = z;
        (&hb2[0][0][0][0])[tid] = z;
    }
    if (tid < H)  wlin[tid] = W_lin[tid];
    if (tid == H) wlin[H]   = b_lin[0];

    // x chunk 0
#pragma unroll
    for (int r = 0; r < 2; ++r) {
        int b = wv + 8 * r;
        xss[0][lane * 17 + b] = input[(size_t)(b0 + b) * TSEQ + lane];
    }

    // ---- persistent A-fragments (unified array, filled per role), split bf16 ----
    // L1 waves: s=0,1 hold W_hh1 (K=64); s=2,3 zero/unused.
    // L2 waves: s=0,1 hold W_ih2 (k=h1), s=2,3 hold W_hh2 (k=h2).
    short8 wah[4][4], wal[4][4];
    bool tok[4];
#pragma unroll
    for (int i = 0; i < 4; ++i) {
        const int tile = rw + 4 * i;      // slot map: {rw, rw+4, rw+8, rw+12}
        tok[i] = (tile < NT);
        const int arow = tile * 16 + n;
        const int cell = arow >> 2, gate = arow & 3;
        const int orow = gate * H + cell;
        const float gsc = (gate == 2) ? TWOLOG2E : LOG2E;
        const bool rok = (arow < 4 * H);
#pragma unroll
        for (int s = 0; s < 4; ++s) {
#pragma unroll
            for (int j = 0; j < 8; ++j) {
                int kk = s * 32 + qd * 8 + j;
                float w = 0.f;
                if (rok) {
                    if (isL1) {
                        if (kk < H) w = gsc * W_hh1[orow * H + kk];
                    } else {
                        if (kk < H)                       w = gsc * W_ih2[orow * H + kk];
                        else if (kk >= 64 && kk < 64 + H) w = gsc * W_hh2[orow * H + (kk - 64)];
                    }
                }
                unsigned short hi = bf16_rne(w);
                wah[i][s][j] = (short)hi;
                wal[i][s][j] = (short)bf16_rne(w - bf16f(hi));
            }
        }
    }

    // ---- per-lane elementwise constants (cell j = tile*4 + quad), pre-scaled ----
    float4v biasv[4], wih1v[4];
    int  cellj[4]; bool cok[4];
#pragma unroll
    for (int i = 0; i < 4; ++i) {
        const int tile = rw + 4 * i;
        const int j = tile * 4 + qd;
        cellj[i] = j;
        cok[i]   = tok[i] && (j < H);
#pragma unroll
        for (int r = 0; r < 4; ++r) {
            const float gsc = (r == 2) ? TWOLOG2E : LOG2E;
            float bv = 0.f, wv1 = 0.f;
            if (cok[i]) {
                const int orow = r * H + j;
                bv  = isL1 ? gsc * (b_ih1[orow] + b_hh1[orow])
                           : gsc * (b_ih2[orow] + b_hh2[orow]);
                wv1 = isL1 ? gsc * W_ih1[orow] : 0.f;
            }
            biasv[i][r] = bv;
            wih1v[i][r] = wv1;
        }
    }

    short8 f1h[2], f1l[2], f2h[2], f2l[2];
    {
        short8 z = {0,0,0,0,0,0,0,0};
        f1h[0]=z; f1h[1]=z; f1l[0]=z; f1l[1]=z;
        f2h[0]=z; f2h[1]=z; f2l[0]=z; f2l[1]=z;
    }
    float c[4] = {0.f,0.f,0.f,0.f};       // c1 on L1 waves, c2 on L2 waves

    __syncthreads();

#pragma unroll 1
    for (int ph = 0; ph < TSEQ + 2; ++ph) {
        const int p  = ph & 1;
        const int cp = (ph >> 6) & 1;

        // mid-chunk x prefetch (barrier-free double buffer)
        if ((ph & 63) == 32 && ph + 32 < TSEQ) {
#pragma unroll
            for (int r = 0; r < 2; ++r) {
                int b = wv + 8 * r;
                xss[cp ^ 1][lane * 17 + b] = input[(size_t)(b0 + b) * TSEQ + (ph + 32) + lane];
            }
        }

        // ---- frag loads (parity p^1) ----
        if (isL1) {
            if (ph < TSEQ) {
#pragma unroll
                for (int s = 0; s < 2; ++s) {
                    f1h[s] = hb1[p ^ 1][0][s][lane];
                    f1l[s] = hb1[p ^ 1][1][s][lane];
                }
            }
        } else if (ph >= 1 && ph <= TSEQ) {
#pragma unroll
            for (int s = 0; s < 2; ++s) {
                f1h[s] = hb1[p ^ 1][0][s][lane];
                f1l[s] = hb1[p ^ 1][1][s][lane];
                f2h[s] = hb2[p ^ 1][0][s][lane];
                f2l[s] = hb2[p ^ 1][1][s][lane];
            }
        }

        // ---- y(ph-2): wave 1 (an L1 wave with 3 real slots) ----
        if (wv == 1 && ph >= 2) {
            const int st = ph - 2;
            const int b = lane & 15, kg = lane >> 4;
            float a = 0.f;
#pragma unroll
            for (int it = 0; it < 13; ++it) {
                int j = kg + it * 4;
                if (j < H) a = fmaf(wlin[j], h2f[p ^ 1][j * 16 + b], a);
            }
            a += __shfl_xor(a, 16, 64);
            a += __shfl_xor(a, 32, 64);
            if (kg == 0) ybf[b][st & 63] = a + wlin[H];
            if ((st & 63) == 63) {        // flush steps [st-63, st]
                int tb = st - 63;
#pragma unroll
                for (int r = 0; r < BB; ++r)
                    out[(size_t)(b0 + r) * TSEQ + tb + lane] = ybf[r][lane];
            }
        }

        // ---- stage compute ----
        if (isL1) {
            if (ph < TSEQ) {
                const float xb = xss[cp][(ph & 63) * 17 + n];
                float4v acc[4];
#pragma unroll
                for (int i = 0; i < 4; ++i)
#pragma unroll
                    for (int r = 0; r < 4; ++r)
                        acc[i][r] = fmaf(wih1v[i][r], xb, biasv[i][r]);
                // dummy slots run too (zero weights) — keeps scheduling straight-line
#pragma unroll
                for (int s = 0; s < 2; ++s)
#pragma unroll
                    for (int i = 0; i < 4; ++i) {
                        acc[i] = __builtin_amdgcn_mfma_f32_16x16x32_bf16(wah[i][s], f1h[s], acc[i], 0, 0, 0);
                        acc[i] = __builtin_amdgcn_mfma_f32_16x16x32_bf16(wah[i][s], f1l[s], acc[i], 0, 0, 0);
                        acc[i] = __builtin_amdgcn_mfma_f32_16x16x32_bf16(wal[i][s], f1h[s], acc[i], 0, 0, 0);
                    }
#pragma unroll
                for (int i = 0; i < 4; ++i) if (tok[i]) {
                    float cn = fmaf(sig_pre(acc[i][1]), c[i], sig_pre(acc[i][0]) * tanh_pre(acc[i][2]));
                    c[i] = cn;
                    float h = sig_pre(acc[i][3]) * tanh_pre(cn * TWOLOG2E);
                    if (cok[i]) {
                        int j = cellj[i];
                        int s = j >> 5, q = (j & 31) >> 3, j7 = j & 7;
                        unsigned short hi = bf16_rne(h);
                        ((short*)&hb1[p][0][s][q * 16 + n])[j7] = (short)hi;
                        ((short*)&hb1[p][1][s][q * 16 + n])[j7] = (short)bf16_rne(h - bf16f(hi));
                    }
                }
            }
        } else {
            if (ph >= 1 && ph <= TSEQ) {
                float4v acc[4];
#pragma unroll
                for (int i = 0; i < 4; ++i) acc[i] = biasv[i];
#pragma unroll
                for (int s = 0; s < 2; ++s)
#pragma unroll
                    for (int i = 0; i < 4; ++i) {
                        acc[i] = __builtin_amdgcn_mfma_f32_16x16x32_bf16(wah[i][s], f1h[s], acc[i], 0, 0, 0);
                        acc[i] = __builtin_amdgcn_mfma_f32_16x16x32_bf16(wah[i][s], f1l[s], acc[i], 0, 0, 0);
                        acc[i] = __builtin_amdgcn_mfma_f32_16x16x32_bf16(wal[i][s], f1h[s], acc[i], 0, 0, 0);
                    }
#pragma unroll
                for (int s = 0; s < 2; ++s)
#pragma unroll
                    for (int i = 0; i < 4; ++i) {
                        acc[i] = __builtin_amdgcn_mfma_f32_16x16x32_bf16(wah[i][s + 2], f2h[s], acc[i], 0, 0, 0);
                        acc[i] = __builtin_amdgcn_mfma_f32_16x16x32_bf16(wah[i][s + 2], f2l[s], acc[i], 0, 0, 0);
                        acc[i] = __builtin_amdgcn_mfma_f32_16x16x32_bf16(wal[i][s + 2], f2h[s], acc[i], 0, 0, 0);
                    }
#pragma unroll
                for (int i = 0; i < 4; ++i) if (tok[i]) {
                    float cn = fmaf(sig_pre(acc[i][1]), c[i], sig_pre(acc[i][0]) * tanh_pre(acc[i][2]));
                    c[i] = cn;
                    float h = sig_pre(acc[i][3]) * tanh_pre(cn * TWOLOG2E);
                    if (cok[i]) {
                        int j = cellj[i];
                        int s = j >> 5, q = (j & 31) >> 3, j7 = j & 7;
                        unsigned short hi = bf16_rne(h);
                        ((short*)&hb2[p][0][s][q * 16 + n])[j7] = (short)hi;
                        ((short*)&hb2[p][1][s][q * 16 + n])[j7] = (short)bf16_rne(h - bf16f(hi));
                        h2f[p][j * 16 + n] = h;
                    }
                }
            }
        }

        __syncthreads();   // publishes h1(ph), h2(ph-1), h2f(ph-1)
    }
}

extern "C" void kernel_launch(void* const* d_in, const int* in_sizes, int n_in,
                              void* d_out, int out_size, void* d_ws, size_t ws_size,
                              hipStream_t stream) {
    const float* input = (const float*)d_in[0];
    const float* W_ih1 = (const float*)d_in[1];
    const float* W_hh1 = (const float*)d_in[2];
    const float* b_ih1 = (const float*)d_in[3];
    const float* b_hh1 = (const float*)d_in[4];
    const float* W_ih2 = (const float*)d_in[5];
    const float* W_hh2 = (const float*)d_in[6];
    const float* b_ih2 = (const float*)d_in[7];
    const float* b_hh2 = (const float*)d_in[8];
    const float* W_lin = (const float*)d_in[9];
    const float* b_lin = (const float*)d_in[10];

    lstm_pipe_kernel<<<dim3(2048 / BB), dim3(THREADS), 0, stream>>>(
        input, W_ih1, W_hh1, b_ih1, b_hh1,
        W_ih2, W_hh2, b_ih2, b_hh2, W_lin, b_lin,
        (float*)d_out);
}